// Round 10
// baseline (197.199 us; speedup 1.0000x reference)
//
#include <hip/hip_runtime.h>
#include <hip/hip_fp16.h>

#define Bx 2
#define Cx 256
#define Hx 128
#define Wx 128
#define HWx (Hx*Wx)     // 16384
#define Ox 256
#define Kx 9
#define NOFF 27         // 3*K offset-conv output channels
#define KK 2304         // 9 taps * 256 channels

#define SLOT 80         // shorts per As slot (16B-aligned rows, 4-way max conflict)
#define NSLOT 102       // 3 rows x 34 px
#define ABUF (NSLOT*SLOT)

// k35 window geometry: 7 rows x 72 cols around the block's half-row.
#define WROWS 7
#define WCOLS 72
#define WCELLS (WROWS*WCOLS)   // 504 (< 511 sentinel)

typedef __attribute__((ext_vector_type(8))) _Float16 f16x8;
typedef __attribute__((ext_vector_type(4))) float f32x4;

// ws layout (float offsets):
//   tmp_t [0, 1048576)             B*HW*32  (27 used, pad 32; [b][hw][oc])
//   wbf   [1048640, 1085504)       f16 k1 B-fragments [144 frag][64 lane][8]
//                                  (coalesced 1KB loads in k1 -- R7 win)
//   xtb   [1085504, 5279808)       f16 x transposed [b][hw][c] (16.8 MB)
//   wq    [5279808, 5312576)       f16 weight [o][c] row-major (k35, R6 codegen)
//   stats [5312576, 5312608)       18 floats: sum of exp(logit) per (b,k)

__device__ __forceinline__ unsigned short f2h(float f) {
    return __half_as_ushort(__float2half_rn(f));
}

// Fused: blocks [0,2048) transpose+convert x[b][c][hw] -> xtb[b][hw][c] f16
// (64x64 tiles via LDS); blocks [2048,2592) build weight tables (wbf + wq).
// Block 2048 also zeroes the stats accumulator (stream-ordered before k1).
__global__ __launch_bounds__(256) void k_pt(
        const float* __restrict__ x, const float* __restrict__ w_off,
        const float* __restrict__ weight,
        unsigned short* __restrict__ xtb, unsigned short* __restrict__ wbf,
        unsigned short* __restrict__ wq, float* __restrict__ stats) {
    if (blockIdx.x >= 2048) {
        if (blockIdx.x == 2048 && threadIdx.x < 32) stats[threadIdx.x] = 0.f;
        int i = (blockIdx.x - 2048) * 256 + threadIdx.x;
        if (i < 73728) {
            int e    = i & 7;
            int lane = (i >> 3) & 63;
            int frag = i >> 9;            // 0..143
            int t    = frag % 9;
            int sph  = frag / 9;          // wn*8 + ph*2 + s
            int s    = sph & 1;
            int ph   = (sph >> 1) & 3;
            int wn   = sph >> 3;
            int col  = lane & 15, quad = lane >> 4;
            int oc   = wn * 16 + col;
            int c    = ph * 64 + s * 32 + quad * 8 + e;
            float v  = (oc < NOFF) ? w_off[(oc * Cx + c) * 9 + t] : 0.f;
            wbf[i] = f2h(v);
        } else {
            int j = i - 73728;            // 0..65535: row-major wq for k35
            wq[j] = f2h(weight[j]);
        }
        return;
    }
    __shared__ float tl[64][65];
    int tid = threadIdx.x;
    int t   = blockIdx.x;
    int b   = t >> 10;          // 1024 tr-blocks per batch (256 hw x 4 c)
    int r2  = t & 1023;
    int hw0 = (r2 >> 2) * 64;
    int c0  = (r2 & 3) * 64;
#pragma unroll
    for (int r = 0; r < 4; r++) {
        int cl = r * 16 + (tid >> 4);
        int hl = (tid & 15) * 4;
        const float4 v = *(const float4*)&x[((size_t)(b * Cx + c0 + cl)) * HWx + hw0 + hl];
        tl[cl][hl + 0] = v.x; tl[cl][hl + 1] = v.y; tl[cl][hl + 2] = v.z; tl[cl][hl + 3] = v.w;
    }
    __syncthreads();
#pragma unroll
    for (int r = 0; r < 4; r++) {
        int hl = r * 16 + (tid >> 4);
        int cl = (tid & 15) * 4;
        ushort4 o;
        o.x = f2h(tl[cl + 0][hl]); o.y = f2h(tl[cl + 1][hl]);
        o.z = f2h(tl[cl + 2][hl]); o.w = f2h(tl[cl + 3][hl]);
        *(ushort4*)&xtb[((size_t)b * HWx + hw0 + hl) * Cx + c0 + cl] = o;
    }
}

// Offset conv. Block = 32 px of one row: M=32, N=32 oc, K=2304.
// Double-buffered LDS staging (1 barrier/phase), B fragments coalesced 1KB loads.
// grid (512, B). Epilogue: exp-sum partials -> atomicAdd stats[b*9+k].
__global__ __launch_bounds__(256, 4) void k1_mfma(
        const unsigned short* __restrict__ xtb, const unsigned short* __restrict__ wbf,
        const float* __restrict__ b_off, float* __restrict__ tmp_t,
        float* __restrict__ stats) {
    int band = blockIdx.x & 7;
    int idx  = blockIdx.x >> 3;       // 0..63
    int y    = band * 16 + (idx >> 2);
    int qt   = idx & 3;
    int px0  = qt * 32;
    int b    = blockIdx.y;

    __shared__ unsigned short As[2 * ABUF];
    __shared__ float wsum[2][9];
    int tid  = threadIdx.x;
    int wave = tid >> 6, lane = tid & 63;
    int quad = lane >> 4, col = lane & 15;
    int wmh  = wave >> 1;             // m-half (px group)
    int wn   = wave & 1;              // n-half (oc group)

    const unsigned short* xb = xtb + (size_t)b * HWx * Cx;
    const unsigned short* sp[4];
    int  sdst[4];
    bool sstp[4], sldp[4];
#pragma unroll
    for (int i = 0; i < 4; i++) {
        int u = tid + i * 256;
        bool uv = (u < 816);
        int slot = u >> 3;
        int ci   = (u & 7) * 8;
        int r = (slot >= 68) ? 2 : (slot >= 34 ? 1 : 0);
        int p = slot - r * 34;
        int yy = y + r - 1;
        int px = px0 + p - 1;
        bool ib = uv && (yy >= 0) && (yy < Hx) && (px >= 0) && (px < Wx);
        int lin = ib ? (yy * Wx + px) : 0;
        sp[i]   = xb + (size_t)lin * Cx + ci;
        sdst[i] = slot * SLOT + ci;
        sstp[i] = uv;
        sldp[i] = ib;
    }

    f32x4 acc = {};
    const unsigned short* wfb = wbf + ((size_t)(wn * 72 * 64 + lane)) * 8;
    int abase = (wmh * 16 + col) * SLOT + quad * 8;

    {
        uint4 sreg[4];
#pragma unroll
        for (int i = 0; i < 4; i++)
            sreg[i] = sldp[i] ? *(const uint4*)(sp[i]) : make_uint4(0u, 0u, 0u, 0u);
#pragma unroll
        for (int i = 0; i < 4; i++)
            if (sstp[i]) *(uint4*)&As[sdst[i]] = sreg[i];
    }
    __syncthreads();

#pragma unroll 1
    for (int ph = 0; ph < 4; ph++) {
        const unsigned short* Ab = As + (ph & 1) * ABUF;
        unsigned short*       Aw = As + ((ph & 1) ^ 1) * ABUF;
        uint4 sreg[4];
        if (ph < 3) {
#pragma unroll
            for (int i = 0; i < 4; i++)
                sreg[i] = sldp[i] ? *(const uint4*)(sp[i] + (ph + 1) * 64)
                                  : make_uint4(0u, 0u, 0u, 0u);
        }
#pragma unroll
        for (int s = 0; s < 2; s++) {
            int fbase = (ph * 2 + s) * 9;
            f16x8 breg[9];
#pragma unroll
            for (int t = 0; t < 9; t++)
                breg[t] = *(const f16x8*)(wfb + ((size_t)(fbase + t) << 9));
#pragma unroll
            for (int r = 0; r < 3; r++)
#pragma unroll
            for (int dc = 0; dc < 3; dc++) {
                f16x8 a0 = *(const f16x8*)&Ab[(r * 34 + dc) * SLOT + abase + s * 32];
                acc = __builtin_amdgcn_mfma_f32_16x16x32_f16(a0, breg[r * 3 + dc], acc, 0, 0, 0);
            }
        }
        if (ph < 3) {
#pragma unroll
            for (int i = 0; i < 4; i++)
                if (sstp[i]) *(uint4*)&Aw[sdst[i]] = sreg[i];
        }
        __syncthreads();
    }

    float* orow = tmp_t + ((size_t)(b * HWx) + (size_t)y * Wx + px0) * 32;
    int oc = wn * 16 + col;
    float bo = (oc < NOFF) ? b_off[oc] : 0.f;
#pragma unroll
    for (int r4 = 0; r4 < 4; r4++) {
        int pxd = wmh * 16 + quad * 4 + r4;
        float v = acc[r4] + bo;
        acc[r4] = v;
        orow[(size_t)pxd * 32 + oc] = v;
    }

    float s4 = __expf(acc[0]) + __expf(acc[1]) + __expf(acc[2]) + __expf(acc[3]);
    s4 += __shfl_xor(s4, 16);
    s4 += __shfl_xor(s4, 32);
    if (wn == 1 && quad == 0 && col >= 2 && col <= 10)
        wsum[wmh][col - 2] = s4;
    __syncthreads();
    if (tid < 9)
        atomicAdd(&stats[b * 9 + tid], wsum[0][tid] + wsum[1][tid]);
}

// Fused sample + 1x1 conv, LDS-staged gather. Block = 64 px (one half-row).
// Per 32-ch chunk (8 phases): stage 7x72 window cells (XOR-swizzled slots) ->
// gather all 64 px in one 36-iter LDS loop (4 lanes/px x 8ch) -> Asc[64][40]
// -> MFMA K=32 chunk into persistent acc (same K order -> bit-identical GEMM).
// Out-of-window corners use packed global fallback (correct for ANY offsets).
// NOTE: sst9 already contains the x256 f16-range boost (256/stats) -- R9's
// extra *256 double-scaled the mask (absmax 7e-2 = 255 * |out-bias|max).
__global__ __launch_bounds__(256) void k35_fused(
        const unsigned short* __restrict__ xtb, const float* __restrict__ tmp_t,
        const float* __restrict__ stats, const unsigned short* __restrict__ wq,
        const float* __restrict__ bias, float* __restrict__ out) {
    __shared__ int2 lop[64][37];              // {half2 weight (x256), (lin<<9)|cell}
    __shared__ unsigned short win[WCELLS * 32];  // [cell][4 slots x 8ch], slot^=(cell>>1)&3
    __shared__ unsigned short Asc[64 * 40];   // [px][32ch] pitch 40 shorts
    __shared__ float sst9[9];                 // 256 / sum_exp
    int tid  = threadIdx.x;
    int band = blockIdx.x & 7;
    int sub  = blockIdx.x >> 3;
    int b    = blockIdx.y;
    int px0  = (band * 32 + sub) * 64;
    int y    = px0 >> 7;                      // block's row
    int x0   = px0 & (Wx - 1);                // 0 or 64

    if (tid < 9) sst9[tid] = 256.f / stats[b * Kx + tid];
    __syncthreads();

    // build per-corner weights + packed (global lin, window cell) indices
    for (int u = tid; u < 576; u += 256) {
        int px = u / 9, k = u - px * 9;
        int hw = px0 + px;
        int yy = hw >> 7;
        int xx = hw & (Wx - 1);
        const float* trow = tmp_t + ((size_t)b * HWx + hw) * 32;
        float dy = trow[2 * k];
        float dx = trow[2 * k + 1];
        float lg = trow[18 + k];
        float m  = __expf(lg) * sst9[k];      // x256 scale is inside sst9
        float py = dy + (float)(k / 3 - 1 + yy);
        float px_ = dx + (float)(k % 3 - 1 + xx);
        float fy = floorf(py), fx = floorf(px_);
        int y0 = (int)fy, x0c = (int)fx;
        float ly = py - fy, lx = px_ - fx;
        float w00 = (1.f - ly) * (1.f - lx) * m;
        float w01 = (1.f - ly) * lx * m;
        float w10 = ly * (1.f - lx) * m;
        float w11 = ly * lx * m;
        int y1 = y0 + 1, x1 = x0c + 1;
        bool vy0 = (y0 >= 0) & (y0 < Hx), vy1 = (y1 >= 0) & (y1 < Hx);
        bool vx0 = (x0c >= 0) & (x0c < Wx), vx1 = (x1 >= 0) & (x1 < Wx);
        int cy0 = min(max(y0, 0), Hx - 1), cy1 = min(max(y1, 0), Hx - 1);
        int cx0 = min(max(x0c, 0), Wx - 1), cx1 = min(max(x1, 0), Wx - 1);
        float a00 = (vy0 && vx0) ? w00 : 0.f;
        float a01 = (vy0 && vx1) ? w01 : 0.f;
        float a10 = (vy1 && vx0) ? w10 : 0.f;
        float a11 = (vy1 && vx1) ? w11 : 0.f;
#pragma unroll
        for (int c = 0; c < 4; c++) {
            int cy = (c < 2) ? cy0 : cy1;
            int cx = (c & 1) ? cx1 : cx0;
            float aw = (c == 0) ? a00 : (c == 1) ? a01 : (c == 2) ? a10 : a11;
            int rr = cy - (y - 3);
            int rc = cx - (x0 - 4);
            int cell = (rr >= 0 && rr < WROWS && rc >= 0 && rc < WCOLS)
                     ? (rr * WCOLS + rc) : 511;
            __half2 wh = __half2half2(__float2half_rn(aw));
            int2 pk;
            pk.x = *(int*)&wh;
            pk.y = ((cy * Wx + cx) << 9) | cell;
            lop[px][4 * k + c] = pk;
        }
    }

    // phase-invariant staging descriptors: 2016 (cell,octet) tasks / 256 thr
    const unsigned short* xb = xtb + (size_t)b * HWx * Cx;
    const unsigned short* wsp[8];
    int wdst[8];
#pragma unroll
    for (int i = 0; i < 8; i++) {
        int u = tid + i * 256;
        if (u < WCELLS * 4) {
            int cell = u >> 2, qs = u & 3;
            int wr = cell / WCOLS, wc = cell - wr * WCOLS;
            int row = min(max(y - 3 + wr, 0), Hx - 1);
            int cg  = min(max(x0 - 4 + wc, 0), Wx - 1);
            wsp[i]  = xb + ((size_t)(row * Wx + cg)) * Cx + qs * 8;
            wdst[i] = cell * 32 + (qs ^ ((cell >> 1) & 3)) * 8;
        } else {
            wsp[i]  = xb;           // dummy, never stored
            wdst[i] = -1;
        }
    }

    int wave = tid >> 6, lane = tid & 63;
    int g    = lane >> 2;             // px group within wave
    int q    = lane & 3;              // ch octet
    int mypx = wave * 16 + g;
    int quad = lane >> 4, col = lane & 15;
    const __half2 uns = __half2half2(__float2half_rn(1.f / 256.f));
    f32x4 acc[4][4] = {};

    // stage phase 0
    __syncthreads();                  // lop ready (and win not yet read)
#pragma unroll
    for (int i = 0; i < 8; i++)
        if (wdst[i] >= 0) *(uint4*)&win[wdst[i]] = *(const uint4*)(wsp[i]);
    __syncthreads();

#pragma unroll 1
    for (int p = 0; p < 8; p++) {
        // gather: my px, ch [p*32 + q*8, +8)
        __half2 a0 = __half2half2(__ushort_as_half(0));
        __half2 a1 = a0, a2 = a0, a3 = a0;
#pragma unroll
        for (int j = 0; j < 36; j++) {
            int2 t = lop[mypx][j];
            __half2 w = *(__half2*)&t.x;
            int cell = t.y & 511;
            uint4 v;
            if (cell != 511) {
                int sl = q ^ ((cell >> 1) & 3);
                v = *(const uint4*)&win[cell * 32 + sl * 8];
            } else {
                v = *(const uint4*)(xb + ((size_t)(t.y >> 9)) * Cx + p * 32 + q * 8);
            }
            a0 = __hfma2(w, *(__half2*)&v.x, a0);
            a1 = __hfma2(w, *(__half2*)&v.y, a1);
            a2 = __hfma2(w, *(__half2*)&v.z, a2);
            a3 = __hfma2(w, *(__half2*)&v.w, a3);
        }
        a0 = __hmul2(a0, uns); a1 = __hmul2(a1, uns);
        a2 = __hmul2(a2, uns); a3 = __hmul2(a3, uns);
        uint4 r;
        r.x = *(unsigned*)&a0; r.y = *(unsigned*)&a1;
        r.z = *(unsigned*)&a2; r.w = *(unsigned*)&a3;
        *(uint4*)&Asc[mypx * 40 + q * 8] = r;
        __syncthreads();              // Asc ready; all waves done reading win(p)

        // issue next-phase staging early (writes win; safe after barrier),
        // then GEMM this chunk (reads Asc + wq) -- loads overlap MFMA.
        if (p < 7) {
#pragma unroll
            for (int i = 0; i < 8; i++)
                if (wdst[i] >= 0)
                    *(uint4*)&win[wdst[i]] = *(const uint4*)(wsp[i] + (p + 1) * 32);
        }
        f16x8 av[4], wv[4];
#pragma unroll
        for (int nt = 0; nt < 4; nt++)
            wv[nt] = *(const f16x8*)(wq + (size_t)(wave * 64 + nt * 16 + col) * Cx + p * 32 + quad * 8);
#pragma unroll
        for (int mt = 0; mt < 4; mt++)
            av[mt] = *(const f16x8*)&Asc[(mt * 16 + col) * 40 + quad * 8];
#pragma unroll
        for (int mt = 0; mt < 4; mt++)
#pragma unroll
            for (int nt = 0; nt < 4; nt++)
                acc[mt][nt] = __builtin_amdgcn_mfma_f32_16x16x32_f16(av[mt], wv[nt], acc[mt][nt], 0, 0, 0);
        __syncthreads();              // win(p+1) staged + Asc reads drained
    }

#pragma unroll
    for (int nt = 0; nt < 4; nt++) {
        int oc = wave * 64 + nt * 16 + col;
        float bo = bias[oc];
#pragma unroll
        for (int mt = 0; mt < 4; mt++) {
            int hw = px0 + mt * 16 + quad * 4;
            float4 v;
            v.x = acc[mt][nt][0] + bo; v.y = acc[mt][nt][1] + bo;
            v.z = acc[mt][nt][2] + bo; v.w = acc[mt][nt][3] + bo;
            *(float4*)&out[((size_t)(b * Ox + oc)) * HWx + hw] = v;
        }
    }
}

extern "C" void kernel_launch(void* const* d_in, const int* in_sizes, int n_in,
                              void* d_out, int out_size, void* d_ws, size_t ws_size,
                              hipStream_t stream) {
    const float*    x      = (const float*)d_in[0];
    const float*    w_off  = (const float*)d_in[1];
    const float*    b_off  = (const float*)d_in[2];
    const float*    weight = (const float*)d_in[3];
    const float*    bias   = (const float*)d_in[4];
    float* out = (float*)d_out;
    float* ws  = (float*)d_ws;

    float*          tmp_t = ws;
    unsigned short* wbf   = (unsigned short*)(ws + 1048640);
    unsigned short* xtb   = (unsigned short*)(ws + 1085504);
    unsigned short* wq    = (unsigned short*)(ws + 5279808);
    float*          stats = ws + 5312576;

    k_pt<<<dim3(2592), 256, 0, stream>>>(x, w_off, weight, xtb, wbf, wq, stats);
    k1_mfma<<<dim3(512, Bx), 256, 0, stream>>>(xtb, wbf, b_off, tmp_t, stats);
    k35_fused<<<dim3(256, Bx), 256, 0, stream>>>(xtb, tmp_t, stats, wq, bias, out);
}

// Round 11
// 145.367 us; speedup vs baseline: 1.3566x; 1.3566x over previous
//
#include <hip/hip_runtime.h>
#include <hip/hip_fp16.h>

#define Bx 2
#define Cx 256
#define Hx 128
#define Wx 128
#define HWx (Hx*Wx)     // 16384
#define Ox 256
#define Kx 9
#define NOFF 27         // 3*K offset-conv output channels
#define KK 2304         // 9 taps * 256 channels

#define SLOT 80         // shorts per As slot (16B-aligned rows, 4-way max conflict)
#define NSLOT 102       // 3 rows x 34 px
#define ABUF (NSLOT*SLOT)

typedef __attribute__((ext_vector_type(8))) _Float16 f16x8;
typedef __attribute__((ext_vector_type(4))) float f32x4;

// ws layout (float offsets):
//   tmp_t [0, 1048576)             B*HW*32  (27 used, pad 32; [b][hw][oc])
//   wbf   [1048640, 1085504)       f16 k1 B-fragments [144 frag][64 lane][8]
//                                  (coalesced 1KB loads in k1 -- R7 win, -16us)
//   xtb   [1085504, 5279808)       f16 x transposed [b][hw][c] (16.8 MB)
//   wq    [5279808, 5312576)       f16 weight [o][c] row-major (k35 -- R6 codegen;
//                                  every restructure of k35 regressed: R5 TLP+
//                                  VGPR-cap -10us, R7 fragment-B regalloc -26us,
//                                  R10 LDS-staged gather -50us w/ 2.96M bank
//                                  conflicts + 10% occupancy)
//   stats [5312576, 5312608)       18 floats: sum of exp(logit) per (b,k)

__device__ __forceinline__ unsigned short f2h(float f) {
    return __half_as_ushort(__float2half_rn(f));
}

// Fused: blocks [0,2048) transpose+convert x[b][c][hw] -> xtb[b][hw][c] f16
// (64x64 tiles via LDS); blocks [2048,2592) build weight tables (wbf + wq).
// Block 2048 also zeroes the stats accumulator (stream-ordered before k1).
__global__ __launch_bounds__(256) void k_pt(
        const float* __restrict__ x, const float* __restrict__ w_off,
        const float* __restrict__ weight,
        unsigned short* __restrict__ xtb, unsigned short* __restrict__ wbf,
        unsigned short* __restrict__ wq, float* __restrict__ stats) {
    if (blockIdx.x >= 2048) {
        if (blockIdx.x == 2048 && threadIdx.x < 32) stats[threadIdx.x] = 0.f;
        int i = (blockIdx.x - 2048) * 256 + threadIdx.x;
        if (i < 73728) {
            int e    = i & 7;
            int lane = (i >> 3) & 63;
            int frag = i >> 9;            // 0..143
            int t    = frag % 9;
            int sph  = frag / 9;          // wn*8 + ph*2 + s
            int s    = sph & 1;
            int ph   = (sph >> 1) & 3;
            int wn   = sph >> 3;
            int col  = lane & 15, quad = lane >> 4;
            int oc   = wn * 16 + col;
            int c    = ph * 64 + s * 32 + quad * 8 + e;
            float v  = (oc < NOFF) ? w_off[(oc * Cx + c) * 9 + t] : 0.f;
            wbf[i] = f2h(v);
        } else {
            int j = i - 73728;            // 0..65535: row-major wq for k35
            wq[j] = f2h(weight[j]);
        }
        return;
    }
    __shared__ float tl[64][65];
    int tid = threadIdx.x;
    int t   = blockIdx.x;
    int b   = t >> 10;          // 1024 tr-blocks per batch (256 hw x 4 c)
    int r2  = t & 1023;
    int hw0 = (r2 >> 2) * 64;
    int c0  = (r2 & 3) * 64;
#pragma unroll
    for (int r = 0; r < 4; r++) {
        int cl = r * 16 + (tid >> 4);
        int hl = (tid & 15) * 4;
        const float4 v = *(const float4*)&x[((size_t)(b * Cx + c0 + cl)) * HWx + hw0 + hl];
        tl[cl][hl + 0] = v.x; tl[cl][hl + 1] = v.y; tl[cl][hl + 2] = v.z; tl[cl][hl + 3] = v.w;
    }
    __syncthreads();
#pragma unroll
    for (int r = 0; r < 4; r++) {
        int hl = r * 16 + (tid >> 4);
        int cl = (tid & 15) * 4;
        ushort4 o;
        o.x = f2h(tl[cl + 0][hl]); o.y = f2h(tl[cl + 1][hl]);
        o.z = f2h(tl[cl + 2][hl]); o.w = f2h(tl[cl + 3][hl]);
        *(ushort4*)&xtb[((size_t)b * HWx + hw0 + hl) * Cx + c0 + cl] = o;
    }
}

// Offset conv. Block = 32 px of one row: M=32, N=32 oc, K=2304.
// Double-buffered LDS staging (1 barrier/phase), B fragments coalesced 1KB loads.
// grid (512, B). Epilogue: exp-sum partials -> atomicAdd stats[b*9+k].
// (No max subtraction: logits ~N(0,0.5), exp is fp32-safe.)
__global__ __launch_bounds__(256, 4) void k1_mfma(
        const unsigned short* __restrict__ xtb, const unsigned short* __restrict__ wbf,
        const float* __restrict__ b_off, float* __restrict__ tmp_t,
        float* __restrict__ stats) {
    int band = blockIdx.x & 7;
    int idx  = blockIdx.x >> 3;       // 0..63
    int y    = band * 16 + (idx >> 2);
    int qt   = idx & 3;
    int px0  = qt * 32;
    int b    = blockIdx.y;

    __shared__ unsigned short As[2 * ABUF];
    __shared__ float wsum[2][9];
    int tid  = threadIdx.x;
    int wave = tid >> 6, lane = tid & 63;
    int quad = lane >> 4, col = lane & 15;
    int wmh  = wave >> 1;             // m-half (px group)
    int wn   = wave & 1;              // n-half (oc group)

    const unsigned short* xb = xtb + (size_t)b * HWx * Cx;
    const unsigned short* sp[4];
    int  sdst[4];
    bool sstp[4], sldp[4];
#pragma unroll
    for (int i = 0; i < 4; i++) {
        int u = tid + i * 256;
        bool uv = (u < 816);
        int slot = u >> 3;
        int ci   = (u & 7) * 8;
        int r = (slot >= 68) ? 2 : (slot >= 34 ? 1 : 0);
        int p = slot - r * 34;
        int yy = y + r - 1;
        int px = px0 + p - 1;
        bool ib = uv && (yy >= 0) && (yy < Hx) && (px >= 0) && (px < Wx);
        int lin = ib ? (yy * Wx + px) : 0;
        sp[i]   = xb + (size_t)lin * Cx + ci;
        sdst[i] = slot * SLOT + ci;
        sstp[i] = uv;
        sldp[i] = ib;
    }

    f32x4 acc = {};
    const unsigned short* wfb = wbf + ((size_t)(wn * 72 * 64 + lane)) * 8;
    int abase = (wmh * 16 + col) * SLOT + quad * 8;

    {
        uint4 sreg[4];
#pragma unroll
        for (int i = 0; i < 4; i++)
            sreg[i] = sldp[i] ? *(const uint4*)(sp[i]) : make_uint4(0u, 0u, 0u, 0u);
#pragma unroll
        for (int i = 0; i < 4; i++)
            if (sstp[i]) *(uint4*)&As[sdst[i]] = sreg[i];
    }
    __syncthreads();

#pragma unroll 1
    for (int ph = 0; ph < 4; ph++) {
        const unsigned short* Ab = As + (ph & 1) * ABUF;
        unsigned short*       Aw = As + ((ph & 1) ^ 1) * ABUF;
        uint4 sreg[4];
        if (ph < 3) {
#pragma unroll
            for (int i = 0; i < 4; i++)
                sreg[i] = sldp[i] ? *(const uint4*)(sp[i] + (ph + 1) * 64)
                                  : make_uint4(0u, 0u, 0u, 0u);
        }
#pragma unroll
        for (int s = 0; s < 2; s++) {
            int fbase = (ph * 2 + s) * 9;
            f16x8 breg[9];
#pragma unroll
            for (int t = 0; t < 9; t++)
                breg[t] = *(const f16x8*)(wfb + ((size_t)(fbase + t) << 9));
#pragma unroll
            for (int r = 0; r < 3; r++)
#pragma unroll
            for (int dc = 0; dc < 3; dc++) {
                f16x8 a0 = *(const f16x8*)&Ab[(r * 34 + dc) * SLOT + abase + s * 32];
                acc = __builtin_amdgcn_mfma_f32_16x16x32_f16(a0, breg[r * 3 + dc], acc, 0, 0, 0);
            }
        }
        if (ph < 3) {
#pragma unroll
            for (int i = 0; i < 4; i++)
                if (sstp[i]) *(uint4*)&Aw[sdst[i]] = sreg[i];
        }
        __syncthreads();
    }

    float* orow = tmp_t + ((size_t)(b * HWx) + (size_t)y * Wx + px0) * 32;
    int oc = wn * 16 + col;
    float bo = (oc < NOFF) ? b_off[oc] : 0.f;
#pragma unroll
    for (int r4 = 0; r4 < 4; r4++) {
        int pxd = wmh * 16 + quad * 4 + r4;
        float v = acc[r4] + bo;
        acc[r4] = v;
        orow[(size_t)pxd * 32 + oc] = v;
    }

    float s4 = __expf(acc[0]) + __expf(acc[1]) + __expf(acc[2]) + __expf(acc[3]);
    s4 += __shfl_xor(s4, 16);
    s4 += __shfl_xor(s4, 32);
    if (wn == 1 && quad == 0 && col >= 2 && col <= 10)
        wsum[wmh][col - 2] = s4;
    __syncthreads();
    if (tid < 9)
        atomicAdd(&stats[b * 9 + tid], wsum[0][tid] + wsum[1][tid]);
}

// Fused sample + 1x1 conv. Block = 64 px, all 256 ch, all 256 oc.
// EXACT R6 source (measured <=43us): row-major wq B-loads, contiguous-px
// gather mapping, no launch_bounds min-wave clamp (VGPR ~128 for load MLP).
// grid (256, B): band = &7 (XCD), sub = >>3; px0 = (band*32+sub)*64.
__global__ __launch_bounds__(256) void k35_fused(
        const unsigned short* __restrict__ xtb, const float* __restrict__ tmp_t,
        const float* __restrict__ stats, const unsigned short* __restrict__ wq,
        const float* __restrict__ bias, float* __restrict__ out) {
    __shared__ __half2 lwh[64][36];           // (w,w) packed, x256 scale
    __shared__ int     lo[64][36];
    __shared__ unsigned short As[64][264];    // sampled f16, stride 132 dw = 4 mod 32
    __shared__ float sst9[9];                 // 256 / sum_exp
    int tid  = threadIdx.x;
    int band = blockIdx.x & 7;
    int sub  = blockIdx.x >> 3;
    int b    = blockIdx.y;
    int px0  = (band * 32 + sub) * 64;

    if (tid < 9) sst9[tid] = 256.f / stats[b * Kx + tid];
    __syncthreads();

    for (int u = tid; u < 576; u += 256) {
        int px = u / 9, k = u - px * 9;
        int hw = px0 + px;
        int y  = hw >> 7;
        int xx = hw & (Wx - 1);
        const float* trow = tmp_t + ((size_t)b * HWx + hw) * 32;
        float dy = trow[2 * k];
        float dx = trow[2 * k + 1];
        float lg = trow[18 + k];
        float m  = __expf(lg) * sst9[k];
        float py = dy + (float)(k / 3 - 1 + y);
        float px_ = dx + (float)(k % 3 - 1 + xx);
        float fy = floorf(py), fx = floorf(px_);
        int y0 = (int)fy, x0 = (int)fx;
        float ly = py - fy, lx = px_ - fx;
        float w00 = (1.f - ly) * (1.f - lx) * m;
        float w01 = (1.f - ly) * lx * m;
        float w10 = ly * (1.f - lx) * m;
        float w11 = ly * lx * m;
        int y1 = y0 + 1, x1 = x0 + 1;
        bool vy0 = (y0 >= 0) & (y0 < Hx), vy1 = (y1 >= 0) & (y1 < Hx);
        bool vx0 = (x0 >= 0) & (x0 < Wx), vx1 = (x1 >= 0) & (x1 < Wx);
        int cy0 = min(max(y0, 0), Hx - 1), cy1 = min(max(y1, 0), Hx - 1);
        int cx0 = min(max(x0, 0), Wx - 1), cx1 = min(max(x1, 0), Wx - 1);
        float a00 = (vy0 && vx0) ? w00 : 0.f;
        float a01 = (vy0 && vx1) ? w01 : 0.f;
        float a10 = (vy1 && vx0) ? w10 : 0.f;
        float a11 = (vy1 && vx1) ? w11 : 0.f;
        lwh[px][4 * k + 0] = __half2half2(__float2half_rn(a00));  lo[px][4 * k + 0] = cy0 * Wx + cx0;
        lwh[px][4 * k + 1] = __half2half2(__float2half_rn(a01));  lo[px][4 * k + 1] = cy0 * Wx + cx1;
        lwh[px][4 * k + 2] = __half2half2(__float2half_rn(a10));  lo[px][4 * k + 2] = cy1 * Wx + cx0;
        lwh[px][4 * k + 3] = __half2half2(__float2half_rn(a11));  lo[px][4 * k + 3] = cy1 * Wx + cx1;
    }
    __syncthreads();

    int wave = tid >> 6;
    int lane = tid & 63;
    int half = lane >> 5;
    int li   = lane & 31;
    const unsigned short* xb = xtb + (size_t)b * HWx * Cx + li * 8;
    const __half2 uns = __half2half2(__float2half_rn(1.f / 256.f));
#pragma unroll 1
    for (int pass = 0; pass < 8; pass++) {
        int px = pass * 8 + wave * 2 + half;   // contiguous active-px group
        __half2 a0 = __half2half2(__ushort_as_half(0));
        __half2 a1 = a0, a2 = a0, a3 = a0;
#pragma unroll
        for (int j = 0; j < 36; j++) {
            __half2 w = lwh[px][j];
            int   off = lo[px][j];
            uint4 v = *(const uint4*)(xb + (size_t)off * Cx);
            a0 = __hfma2(w, *(__half2*)&v.x, a0);
            a1 = __hfma2(w, *(__half2*)&v.y, a1);
            a2 = __hfma2(w, *(__half2*)&v.z, a2);
            a3 = __hfma2(w, *(__half2*)&v.w, a3);
        }
        a0 = __hmul2(a0, uns); a1 = __hmul2(a1, uns);
        a2 = __hmul2(a2, uns); a3 = __hmul2(a3, uns);
        uint4 r;
        r.x = *(unsigned*)&a0; r.y = *(unsigned*)&a1;
        r.z = *(unsigned*)&a2; r.w = *(unsigned*)&a3;
        *(uint4*)&As[px][li * 8] = r;
    }
    __syncthreads();

    // GEMM: wave covers oc [wave*64, wave*64+64), all 64 px.
    int quad = lane >> 4, col = lane & 15;
    f32x4 acc[4][4] = {};
#pragma unroll
    for (int ki = 0; ki < 8; ki++) {
        int k0 = ki * 32;
        f16x8 a[4], w[4];
#pragma unroll
        for (int mt = 0; mt < 4; mt++)
            a[mt] = *(const f16x8*)&As[mt * 16 + col][k0 + quad * 8];
#pragma unroll
        for (int nt = 0; nt < 4; nt++)
            w[nt] = *(const f16x8*)(wq + (size_t)(wave * 64 + nt * 16 + col) * Cx + k0 + quad * 8);
#pragma unroll
        for (int mt = 0; mt < 4; mt++)
#pragma unroll
            for (int nt = 0; nt < 4; nt++)
                acc[mt][nt] = __builtin_amdgcn_mfma_f32_16x16x32_f16(a[mt], w[nt], acc[mt][nt], 0, 0, 0);
    }

#pragma unroll
    for (int nt = 0; nt < 4; nt++) {
        int oc = wave * 64 + nt * 16 + col;
        float bo = bias[oc];
#pragma unroll
        for (int mt = 0; mt < 4; mt++) {
            int hw = px0 + mt * 16 + quad * 4;
            float4 v;
            v.x = acc[mt][nt][0] + bo; v.y = acc[mt][nt][1] + bo;
            v.z = acc[mt][nt][2] + bo; v.w = acc[mt][nt][3] + bo;
            *(float4*)&out[((size_t)(b * Ox + oc)) * HWx + hw] = v;
        }
    }
}

extern "C" void kernel_launch(void* const* d_in, const int* in_sizes, int n_in,
                              void* d_out, int out_size, void* d_ws, size_t ws_size,
                              hipStream_t stream) {
    const float*    x      = (const float*)d_in[0];
    const float*    w_off  = (const float*)d_in[1];
    const float*    b_off  = (const float*)d_in[2];
    const float*    weight = (const float*)d_in[3];
    const float*    bias   = (const float*)d_in[4];
    float* out = (float*)d_out;
    float* ws  = (float*)d_ws;

    float*          tmp_t = ws;
    unsigned short* wbf   = (unsigned short*)(ws + 1048640);
    unsigned short* xtb   = (unsigned short*)(ws + 1085504);
    unsigned short* wq    = (unsigned short*)(ws + 5279808);
    float*          stats = ws + 5312576;

    k_pt<<<dim3(2592), 256, 0, stream>>>(x, w_off, weight, xtb, wbf, wq, stats);
    k1_mfma<<<dim3(512, Bx), 256, 0, stream>>>(xtb, wbf, b_off, tmp_t, stats);
    k35_fused<<<dim3(256, Bx), 256, 0, stream>>>(xtb, tmp_t, stats, wq, bias, out);
}